// Round 1
// baseline (174.432 us; speedup 1.0000x reference)
//
#include <hip/hip_runtime.h>
#include <math.h>

namespace {

constexpr int B = 32, T = 4096, I = 16, O = 16;
constexpr int BOI = B * O * I; // 8192 = 2^13

__device__ __forceinline__ void channel_params(const float* __restrict__ bc,
                                               const float* __restrict__ rho,
                                               const float* __restrict__ psi,
                                               int o, int i,
                                               float& b0, float& b1, float& a1, float& a2) {
    int oi = o * I + i;
    b0 = bc[oi * 2 + 0];
    b1 = bc[oi * 2 + 1];
    float r     = 1.0f / (1.0f + expf(-rho[oi]));
    float theta = 3.14159265358979323846f / (1.0f + expf(-psi[oi]));
    a1 = -2.0f * r * cosf(theta);
    a2 = r * r;
}

// Pass 1: one thread per (b,o,i,chunk). Run chunk with zero IC, store the
// end state (y[last], y[last-1]) into d1/d2 at [k][boi].
__global__ void pass1_kernel(const float* __restrict__ u, const float* __restrict__ bc,
                             const float* __restrict__ rho, const float* __restrict__ psi,
                             float* __restrict__ d1, float* __restrict__ d2,
                             int C, int L) {
    int g = blockIdx.x * blockDim.x + threadIdx.x; // B*O*I*C threads
    int i = g & 15, o = (g >> 4) & 15, b = (g >> 8) & 31, k = g >> 13;
    float b0, b1, a1, a2;
    channel_params(bc, rho, psi, o, i, b0, b1, a1, a2);
    int t0 = k * L;
    const float* up = u + (b * T + t0) * I + i;
    float uprev = (k == 0) ? 0.0f : up[-I];
    float y1 = 0.0f, y2 = 0.0f;
    for (int t = 0; t < L; ++t) {
        float uc = up[t * I];
        float x = b0 * uc + b1 * uprev;
        float y = x - a1 * y1 - a2 * y2;
        y2 = y1; y1 = y; uprev = uc;
    }
    int idx = k * BOI + (g & (BOI - 1));
    d1[idx] = y1;
    d2[idx] = y2;
}

// Carry scan: one thread per (b,o,i). A = M^L via repeated squaring
// (L is a power of two). In-place: overwrite d[k] with the INCOMING state
// of chunk k, i.e. (y[k*L-1], y[k*L-2]).
__global__ void carry_kernel(const float* __restrict__ bc, const float* __restrict__ rho,
                             const float* __restrict__ psi,
                             float* __restrict__ d1, float* __restrict__ d2,
                             int C, int L) {
    int g = blockIdx.x * blockDim.x + threadIdx.x; // BOI threads
    int i = g & 15, o = (g >> 4) & 15;
    float b0, b1, a1, a2;
    channel_params(bc, rho, psi, o, i, b0, b1, a1, a2);
    float m00 = -a1, m01 = -a2, m10 = 1.0f, m11 = 0.0f;
    for (int e = L; e > 1; e >>= 1) {
        float t00 = m00 * m00 + m01 * m10;
        float t01 = m00 * m01 + m01 * m11;
        float t10 = m10 * m00 + m11 * m10;
        float t11 = m10 * m01 + m11 * m11;
        m00 = t00; m01 = t01; m10 = t10; m11 = t11;
    }
    float s1 = 0.0f, s2 = 0.0f;
    for (int k = 0; k < C; ++k) {
        int idx = k * BOI + g;
        float e1 = d1[idx], e2 = d2[idx];
        d1[idx] = s1; d2[idx] = s2;
        float n1 = m00 * s1 + m01 * s2 + e1;
        float n2 = m10 * s1 + m11 * s2 + e2;
        s1 = n1; s2 = n2;
    }
}

// Pass 2: one thread per (b,o,chunk) holding all 16 input channels in
// registers (16-way ILP). Re-runs the recurrence with the correct incoming
// state and writes out[b,t,o] = sum_i y.
__global__ void pass2_kernel(const float* __restrict__ u, const float* __restrict__ bc,
                             const float* __restrict__ rho, const float* __restrict__ psi,
                             const float* __restrict__ d1, const float* __restrict__ d2,
                             float* __restrict__ out, int C, int L) {
    int g = blockIdx.x * blockDim.x + threadIdx.x; // B*O*C threads
    int o = g & 15, b = (g >> 4) & 31, k = g >> 9;  // O*B = 512 = 2^9
    float b0[I], b1[I], a1[I], a2[I], y1[I], y2[I], uprev[I];
    int boi_base = (b * O + o) * I;
#pragma unroll
    for (int i = 0; i < I; ++i) {
        channel_params(bc, rho, psi, o, i, b0[i], b1[i], a1[i], a2[i]);
        int idx = k * BOI + boi_base + i;
        y1[i] = d1[idx]; // incoming y[t0-1]
        y2[i] = d2[idx]; // incoming y[t0-2]
    }
    int t0 = k * L;
    const float* ubase = u + (b * T + t0) * I;
#pragma unroll
    for (int i = 0; i < I; ++i) uprev[i] = 0.0f;
    if (k != 0) {
#pragma unroll
        for (int i = 0; i < I; ++i) uprev[i] = ubase[i - I];
    }
    float* op = out + (b * T + t0) * O + o;
    for (int t = 0; t < L; ++t) {
        const float4* row = (const float4*)(ubase + t * I);
        float4 q0 = row[0], q1 = row[1], q2 = row[2], q3 = row[3];
        float uc[I];
        *(float4*)&uc[0]  = q0; *(float4*)&uc[4]  = q1;
        *(float4*)&uc[8]  = q2; *(float4*)&uc[12] = q3;
        float yv[I];
#pragma unroll
        for (int i = 0; i < I; ++i) {
            float x = b0[i] * uc[i] + b1[i] * uprev[i];
            float y = x - a1[i] * y1[i] - a2[i] * y2[i];
            y2[i] = y1[i]; y1[i] = y; uprev[i] = uc[i];
            yv[i] = y;
        }
        // tree sum over the 16 channels (depth 4, no serial add chain)
#pragma unroll
        for (int st = 8; st >= 1; st >>= 1) {
#pragma unroll
            for (int j = 0; j < 8; ++j) {
                if (j < st) yv[j] += yv[j + st];
            }
        }
        op[t * O] = yv[0];
    }
}

} // namespace

extern "C" void kernel_launch(void* const* d_in, const int* in_sizes, int n_in,
                              void* d_out, int out_size, void* d_ws, size_t ws_size,
                              hipStream_t stream) {
    const float* u   = (const float*)d_in[0];
    const float* bc  = (const float*)d_in[1];
    const float* rho = (const float*)d_in[2];
    const float* psi = (const float*)d_in[3];
    float* out = (float*)d_out;

    // Pick the largest power-of-two chunk count that fits the workspace.
    int C = 128;
    while (C > 1 && (size_t)C * BOI * 2 * sizeof(float) > ws_size) C >>= 1;
    int L = T / C;

    float* d1 = (float*)d_ws;
    float* d2 = d1 + (size_t)C * BOI;

    pass1_kernel<<<dim3((B * O * I * C) / 256), dim3(256), 0, stream>>>(
        u, bc, rho, psi, d1, d2, C, L);
    carry_kernel<<<dim3(BOI / 256), dim3(256), 0, stream>>>(
        bc, rho, psi, d1, d2, C, L);
    pass2_kernel<<<dim3((B * O * C) / 256), dim3(256), 0, stream>>>(
        u, bc, rho, psi, d1, d2, out, C, L);
}

// Round 2
// 126.497 us; speedup vs baseline: 1.3789x; 1.3789x over previous
//
#include <hip/hip_runtime.h>
#include <math.h>

namespace {

constexpr int B = 32, T = 4096, I = 16, O = 16;
constexpr int BOI = B * O * I; // 8192 = 2^13

__device__ __forceinline__ void channel_params(const float* __restrict__ bc,
                                               const float* __restrict__ rho,
                                               const float* __restrict__ psi,
                                               int o, int i,
                                               float& b0, float& b1, float& a1, float& a2) {
    int oi = o * I + i;
    b0 = bc[oi * 2 + 0];
    b1 = bc[oi * 2 + 1];
    float r     = 1.0f / (1.0f + expf(-rho[oi]));
    float theta = 3.14159265358979323846f / (1.0f + expf(-psi[oi]));
    a1 = -2.0f * r * cosf(theta);
    a2 = r * r;
}

// Pass 1: one thread per (b,o,i,chunk). Run chunk with zero IC, store the
// end state (y[last], y[last-1]) into d1/d2 at [k][boi]. Coalesced stores.
template <int L>
__global__ void pass1_kernel(const float* __restrict__ u, const float* __restrict__ bc,
                             const float* __restrict__ rho, const float* __restrict__ psi,
                             float* __restrict__ d1, float* __restrict__ d2) {
    int g = blockIdx.x * blockDim.x + threadIdx.x; // B*O*I*C threads
    int i = g & 15, o = (g >> 4) & 15, b = (g >> 8) & 31, k = g >> 13;
    float b0, b1, a1, a2;
    channel_params(bc, rho, psi, o, i, b0, b1, a1, a2);
    float na1 = -a1, na2 = -a2;
    int t0 = k * L;
    const float* up = u + (b * T + t0) * I + i;
    float uprev = (k == 0) ? 0.0f : up[-I];
    float y1 = 0.0f, y2 = 0.0f;
#pragma unroll
    for (int t = 0; t < L; ++t) {
        float uc = up[t * I];
        float x = fmaf(b1, uprev, b0 * uc);
        float y = fmaf(na2, y2, fmaf(na1, y1, x));
        y2 = y1; y1 = y; uprev = uc;
    }
    int idx = k * BOI + (g & (BOI - 1));
    d1[idx] = y1;
    d2[idx] = y2;
}

// Parallel affine scan (Hillis-Steele) over the C chunk end-states per
// channel. Operator: s_k = A_L * s_{k-1} + e_k, A_L = M^L constant per
// channel, so A_L^(2^p) is locally computable by squaring — log2(C) LDS
// rounds instead of a 128-iteration serial latency chain. Block = CH
// channels x C chunks. In-place rewrite: slot k becomes the INCOMING state
// of chunk k (exclusive prefix).
template <int C, int L>
__global__ void scan_kernel(const float* __restrict__ bc, const float* __restrict__ rho,
                            const float* __restrict__ psi,
                            float* __restrict__ d1, float* __restrict__ d2) {
    constexpr int CH = 8;
    __shared__ float s1[2][C * CH];
    __shared__ float s2[2][C * CH];
    int tid = threadIdx.x;          // 0 .. C*CH-1
    int c = tid & (CH - 1);
    int k = tid >> 3;               // chunk index
    int ch = blockIdx.x * CH + c;   // global channel in [0, BOI)
    int i = ch & 15, o = (ch >> 4) & 15;
    float b0, b1, a1, a2;
    channel_params(bc, rho, psi, o, i, b0, b1, a1, a2);
    // A_L = M^L via repeated squaring (L is a power of two)
    float m00 = -a1, m01 = -a2, m10 = 1.0f, m11 = 0.0f;
    for (int e = L; e > 1; e >>= 1) {
        float t00 = m00 * m00 + m01 * m10;
        float t01 = m00 * m01 + m01 * m11;
        float t10 = m10 * m00 + m11 * m10;
        float t11 = m10 * m01 + m11 * m11;
        m00 = t00; m01 = t01; m10 = t10; m11 = t11;
    }
    int gidx = k * BOI + ch;
    float vx = d1[gidx], vy = d2[gidx];
    int cur = 0;
    s1[0][tid] = vx; s2[0][tid] = vy;
    __syncthreads();
#pragma unroll
    for (int off = 1; off < C; off <<= 1) {
        float nx = 0.0f, ny = 0.0f;
        if (k >= off) {
            nx = s1[cur][tid - off * CH];
            ny = s2[cur][tid - off * CH];
        }
        vx += m00 * nx + m01 * ny;   // v += A_p * neighbor
        vy += m10 * nx + m11 * ny;
        cur ^= 1;
        s1[cur][tid] = vx; s2[cur][tid] = vy;
        // A_{p+1} = A_p^2
        float t00 = m00 * m00 + m01 * m10;
        float t01 = m00 * m01 + m01 * m11;
        float t10 = m10 * m00 + m11 * m10;
        float t11 = m10 * m01 + m11 * m11;
        m00 = t00; m01 = t01; m10 = t10; m11 = t11;
        __syncthreads();
    }
    // v is now the inclusive prefix over chunks [0..k]; incoming state of
    // chunk k+1 is v_k. Slot 0 gets zeros. Safe in-place: all loads happened
    // before the first barrier, stores after the last.
    if (k == 0) { d1[ch] = 0.0f; d2[ch] = 0.0f; }
    if (k + 1 < C) {
        d1[(k + 1) * BOI + ch] = vx;
        d2[(k + 1) * BOI + ch] = vy;
    }
}

// Pass 2: one thread per (b,o,i,chunk) — 1M threads (vs 65K before).
// Re-runs the recurrence with the correct incoming state; the sum over i is
// a 4-step shuffle butterfly within each 16-lane group (off the recurrence
// critical path); lane i==0 stores (4 writers/wave, contiguous 16B).
template <int L>
__global__ void pass2_kernel(const float* __restrict__ u, const float* __restrict__ bc,
                             const float* __restrict__ rho, const float* __restrict__ psi,
                             const float* __restrict__ d1, const float* __restrict__ d2,
                             float* __restrict__ out) {
    int g = blockIdx.x * blockDim.x + threadIdx.x; // B*O*I*C threads
    int i = g & 15, o = (g >> 4) & 15, b = (g >> 8) & 31, k = g >> 13;
    float b0, b1, a1, a2;
    channel_params(bc, rho, psi, o, i, b0, b1, a1, a2);
    float na1 = -a1, na2 = -a2;
    int idx = k * BOI + (g & (BOI - 1));
    float y1 = d1[idx];  // incoming y[t0-1]
    float y2 = d2[idx];  // incoming y[t0-2]
    int t0 = k * L;
    const float* up = u + (b * T + t0) * I + i;
    float uprev = (k == 0) ? 0.0f : up[-I];
    float* op = out + (b * T + t0) * O + o;
    bool writer = (i == 0);
#pragma unroll
    for (int t = 0; t < L; ++t) {
        float uc = up[t * I];
        float x = fmaf(b1, uprev, b0 * uc);
        float y = fmaf(na2, y2, fmaf(na1, y1, x));
        y2 = y1; y1 = y; uprev = uc;
        float s = y;
        s += __shfl_xor(s, 1);
        s += __shfl_xor(s, 2);
        s += __shfl_xor(s, 4);
        s += __shfl_xor(s, 8);
        if (writer) op[t * O] = s;
    }
}

template <int C>
void launch_all(const float* u, const float* bc, const float* rho, const float* psi,
                float* d1, float* d2, float* out, hipStream_t stream) {
    constexpr int L = T / C;
    pass1_kernel<L><<<dim3((B * O * I * C) / 256), dim3(256), 0, stream>>>(
        u, bc, rho, psi, d1, d2);
    scan_kernel<C, L><<<dim3(BOI / 8), dim3(C * 8), 0, stream>>>(
        bc, rho, psi, d1, d2);
    pass2_kernel<L><<<dim3((B * O * I * C) / 256), dim3(256), 0, stream>>>(
        u, bc, rho, psi, d1, d2, out);
}

} // namespace

extern "C" void kernel_launch(void* const* d_in, const int* in_sizes, int n_in,
                              void* d_out, int out_size, void* d_ws, size_t ws_size,
                              hipStream_t stream) {
    const float* u   = (const float*)d_in[0];
    const float* bc  = (const float*)d_in[1];
    const float* rho = (const float*)d_in[2];
    const float* psi = (const float*)d_in[3];
    float* out = (float*)d_out;

    // Pick the largest chunk count C whose workspace (C*BOI*2 floats) fits.
    int C = 128;
    while (C > 32 && (size_t)C * BOI * 2 * sizeof(float) > ws_size) C >>= 1;

    float* d1 = (float*)d_ws;
    float* d2 = d1 + (size_t)C * BOI;

    if (C == 128)      launch_all<128>(u, bc, rho, psi, d1, d2, out, stream);
    else if (C == 64)  launch_all<64> (u, bc, rho, psi, d1, d2, out, stream);
    else               launch_all<32> (u, bc, rho, psi, d1, d2, out, stream);
}